// Round 2
// baseline (1845.363 us; speedup 1.0000x reference)
//
#include <hip/hip_runtime.h>

#define NB   8
#define LQ   2048
#define DMD  256
#define DIN  512
#define DST  16
#define MT   (NB*LQ)   // 16384 tokens
#define CHK  16        // scan chunks
#define CLEN (LQ/CHK)  // 128 steps per chunk

#define BM 128
#define BN 64
#define BK 16

__device__ __forceinline__ float fsilu(float x){ return x / (1.f + __expf(-x)); }

// ---------------- h = x ----------------
__global__ void k_copy(const float4* __restrict__ src, float4* __restrict__ dst, int n4){
    int i = blockIdx.x*256 + threadIdx.x;
    if(i < n4) dst[i] = src[i];
}

// ---------------- layernorm over DMD=256, one token per 64-lane wave ----------------
__global__ __launch_bounds__(256) void k_ln(const float* __restrict__ h,
                                            const float* __restrict__ g,
                                            const float* __restrict__ b,
                                            float* __restrict__ out){
    int wave = threadIdx.x >> 6, lane = threadIdx.x & 63;
    int m = blockIdx.x*4 + wave;
    const float* row = h + (size_t)m*DMD;
    float4 v = *(const float4*)(row + lane*4);
    float s  = v.x+v.y+v.z+v.w;
    float sq = v.x*v.x+v.y*v.y+v.z*v.z+v.w*v.w;
    #pragma unroll
    for(int o=32;o;o>>=1){ s += __shfl_xor(s,o,64); sq += __shfl_xor(sq,o,64); }
    float mu  = s*(1.f/DMD);
    float var = sq*(1.f/DMD) - mu*mu;
    float rs  = rsqrtf(var + 1e-5f);
    float4 gg = *(const float4*)(g + lane*4);
    float4 bb = *(const float4*)(b + lane*4);
    float4 o4;
    o4.x=(v.x-mu)*rs*gg.x+bb.x; o4.y=(v.y-mu)*rs*gg.y+bb.y;
    o4.z=(v.z-mu)*rs*gg.z+bb.z; o4.w=(v.w-mu)*rs*gg.w+bb.w;
    *(float4*)(out + (size_t)m*DMD + lane*4) = o4;
}

// ---------------- tiled f32 GEMM: C[m,n] = sum_k A[m,k]*Bw[n,k] (+C if accum) ----------------
__global__ __launch_bounds__(256,2) void k_gemm(const float* __restrict__ A,
                                                const float* __restrict__ Bw,
                                                float* __restrict__ C,
                                                int N, int K, int ldc, int atrans, int accum){
    __shared__ float As[BK][BM+4];
    __shared__ float Bs[BK][BN+4];
    const int t  = threadIdx.x;
    const int m0 = blockIdx.x * BM;
    const int n0 = blockIdx.y * BN;
    const int tx = t & 15, ty = t >> 4;
    float acc[8][4];
    #pragma unroll
    for(int i=0;i<8;i++)
        #pragma unroll
        for(int j=0;j<4;j++) acc[i][j]=0.f;

    const float* Abase; int l0 = 0;
    if(atrans){ int bb = m0 / LQ; l0 = m0 % LQ; Abase = A + (size_t)bb*K*LQ; }
    else      { Abase = A + (size_t)m0*K; }

    for(int k0=0; k0<K; k0+=BK){
        if(atrans){
            int tl = t & 127, tk = t >> 7;
            #pragma unroll
            for(int i=0;i<8;i++){
                int k = tk + i*2;
                As[k][tl] = Abase[(size_t)(k0+k)*LQ + l0 + tl];
            }
        } else {
            int tk = t & 15, tr = t >> 4;
            #pragma unroll
            for(int i=0;i<8;i++)
                As[tk][tr+i*16] = Abase[(size_t)(tr+i*16)*K + k0 + tk];
        }
        {
            int tk = t & 15, tn = t >> 4;
            #pragma unroll
            for(int i=0;i<4;i++){
                int n = tn + i*16;
                Bs[tk][n] = (n0+n < N) ? Bw[(size_t)(n0+n)*K + k0+tk] : 0.f;
            }
        }
        __syncthreads();
        #pragma unroll
        for(int k=0;k<BK;k++){
            float a[8], bv[4];
            *(float4*)&a[0] = *(const float4*)&As[k][ty*8];
            *(float4*)&a[4] = *(const float4*)&As[k][ty*8+4];
            *(float4*)&bv[0] = *(const float4*)&Bs[k][tx*4];
            #pragma unroll
            for(int i=0;i<8;i++)
                #pragma unroll
                for(int j=0;j<4;j++) acc[i][j] += a[i]*bv[j];
        }
        __syncthreads();
    }
    int n = n0 + tx*4;
    if(n < N){
        #pragma unroll
        for(int i=0;i<8;i++){
            float4* cp = (float4*)(C + (size_t)(m0+ty*8+i)*ldc + n);
            float4 v = make_float4(acc[i][0],acc[i][1],acc[i][2],acc[i][3]);
            if(accum){ float4 o = *cp; v.x+=o.x; v.y+=o.y; v.z+=o.z; v.w+=o.w; }
            *cp = v;
        }
    }
}

// ---------------- causal depthwise conv(4) + SiLU + transpose to uT[b,d,l] ----------------
__global__ __launch_bounds__(256) void k_conv(const float* __restrict__ xz,
                                              const float* __restrict__ cw,
                                              const float* __restrict__ cb,
                                              float* __restrict__ uT){
    __shared__ float us[67][65];
    int lt0 = blockIdx.x*64, d0 = blockIdx.y*64, b = blockIdx.z;
    int t = threadIdx.x;
    for(int idx=t; idx<67*64; idx+=256){
        int r = idx >> 6, c = idx & 63;
        int l = lt0 - 3 + r;
        us[r][c] = (l >= 0) ? xz[((size_t)(b*LQ + l))*1024 + d0 + c] : 0.f;
    }
    __syncthreads();
    int dl = t >> 2, lg = t & 3;
    int d = d0 + dl;
    float w0=cw[d*4+0], w1=cw[d*4+1], w2=cw[d*4+2], w3=cw[d*4+3];
    float bias = cb[d];
    float o[16];
    #pragma unroll
    for(int i=0;i<16;i++){
        int ll = lg*16 + i;
        float a = bias + w0*us[ll][dl] + w1*us[ll+1][dl] + w2*us[ll+2][dl] + w3*us[ll+3][dl];
        o[i] = fsilu(a);
    }
    float* dst = uT + ((size_t)(b*DIN + d))*LQ + lt0 + lg*16;
    #pragma unroll
    for(int i=0;i<4;i++)
        *(float4*)(dst + i*4) = make_float4(o[i*4],o[i*4+1],o[i*4+2],o[i*4+3]);
}

// ---------------- dt = softplus(dbc[:, :16] @ dtw^T + dtb), write dtT[b,d,l] ----------------
__global__ __launch_bounds__(256) void k_dt(const float* __restrict__ dbc,
                                            const float* __restrict__ w,
                                            const float* __restrict__ bias,
                                            float* __restrict__ dtT){
    int l = blockIdx.x*256 + threadIdx.x;
    int d = blockIdx.y, b = blockIdx.z;
    const float* row = dbc + (size_t)(b*LQ + l)*48;
    float4 r0 = *(const float4*)(row);
    float4 r1 = *(const float4*)(row+4);
    float4 r2 = *(const float4*)(row+8);
    float4 r3 = *(const float4*)(row+12);
    const float* wd = w + d*16;
    float acc = bias[d]
        + r0.x*wd[0] + r0.y*wd[1] + r0.z*wd[2] + r0.w*wd[3]
        + r1.x*wd[4] + r1.y*wd[5] + r1.z*wd[6] + r1.w*wd[7]
        + r2.x*wd[8] + r2.y*wd[9] + r2.z*wd[10]+ r2.w*wd[11]
        + r3.x*wd[12]+ r3.y*wd[13]+ r3.z*wd[14]+ r3.w*wd[15];
    float sp = (acc > 20.f) ? acc : log1pf(__expf(acc));
    dtT[((size_t)(b*DIN + d))*LQ + l] = sp;
}

// ---------------- transpose dbc[:,16:48] -> BT[b,s,l], CT[b,s,l] ----------------
__global__ __launch_bounds__(256) void k_bct(const float* __restrict__ dbc,
                                             float* __restrict__ BT, float* __restrict__ CT){
    int l = blockIdx.x*256 + threadIdx.x;
    int b = blockIdx.y;
    const float* row = dbc + (size_t)(b*LQ + l)*48 + 16;
    float v[32];
    #pragma unroll
    for(int j=0;j<8;j++) *(float4*)&v[j*4] = *(const float4*)(row + j*4);
    #pragma unroll
    for(int s=0;s<DST;s++){
        BT[((size_t)(b*DST+s))*LQ + l] = v[s];
        CT[((size_t)(b*DST+s))*LQ + l] = v[16+s];
    }
}

// ---------------- scan phase 1: per-chunk local scan (h0=0) -> S, sumdt ----------------
// lane: s = lane&15, dl = lane>>4; wave covers 4 d-channels x 16 states
__global__ __launch_bounds__(256) void k_scan1(const float* __restrict__ dtT,
                                               const float* __restrict__ uT,
                                               const float* __restrict__ BT,
                                               const float* __restrict__ A_log,
                                               float* __restrict__ S,
                                               float* __restrict__ sumdt){
    int b = blockIdx.z, c = blockIdx.y;
    int t = threadIdx.x;
    int lane = t & 63, wave = t >> 6;
    int s = lane & 15, dl = lane >> 4;
    int d = blockIdx.x*16 + wave*4 + dl;
    float Aa = -__expf(A_log[d*DST + s]);
    const float4* dtp = (const float4*)(dtT + ((size_t)b*DIN + d)*LQ + c*CLEN);
    const float4* up  = (const float4*)(uT  + ((size_t)b*DIN + d)*LQ + c*CLEN);
    const float4* Bp  = (const float4*)(BT  + ((size_t)b*DST + s)*LQ + c*CLEN);
    float hh = 0.f, sdt = 0.f;
    float4 dt4 = dtp[0], u4 = up[0], B4 = Bp[0];
    for(int g=0; g<CLEN/4; g++){
        float4 nd, nu, nB;
        if(g < CLEN/4 - 1){ nd = dtp[g+1]; nu = up[g+1]; nB = Bp[g+1]; }
        float dtv[4] = {dt4.x,dt4.y,dt4.z,dt4.w};
        float uv[4]  = {u4.x,u4.y,u4.z,u4.w};
        float Bv[4]  = {B4.x,B4.y,B4.z,B4.w};
        #pragma unroll
        for(int j=0;j<4;j++){
            float dA = __expf(dtv[j]*Aa);
            hh = hh*dA + dtv[j]*uv[j]*Bv[j];
            sdt += dtv[j];
        }
        dt4=nd; u4=nu; B4=nB;
    }
    size_t o = (((size_t)b*CHK + c)*DIN + d)*DST + s;
    S[o] = hh;
    if(s == 0) sumdt[((size_t)b*CHK + c)*DIN + d] = sdt;
}

// ---------------- scan phase 2: serial combine over chunks -> H (chunk-initial states) ----
__global__ __launch_bounds__(256) void k_scan2(const float* __restrict__ S,
                                               const float* __restrict__ sumdt,
                                               const float* __restrict__ A_log,
                                               float* __restrict__ H){
    int idx = blockIdx.x*256 + threadIdx.x;   // (b, d, s)
    int s = idx & 15;
    int d = (idx >> 4) & (DIN-1);
    int b = idx >> 13;
    float Aa = -__expf(A_log[d*DST + s]);
    float hh = 0.f;
    for(int c=0; c<CHK; c++){
        size_t o = (((size_t)b*CHK + c)*DIN + d)*DST + s;
        H[o] = hh;
        float P = __expf(Aa * sumdt[((size_t)b*CHK + c)*DIN + d]);
        hh = hh*P + S[o];
    }
}

// ---------------- scan phase 3: per-chunk re-scan from H, emit yT ----------------
__global__ __launch_bounds__(256) void k_scan3(const float* __restrict__ dtT,
                                               const float* __restrict__ uT,
                                               const float* __restrict__ BT,
                                               const float* __restrict__ CT,
                                               const float* __restrict__ A_log,
                                               const float* __restrict__ Dpv,
                                               const float* __restrict__ H,
                                               float* __restrict__ yT){
    int b = blockIdx.z, c = blockIdx.y;
    int t = threadIdx.x;
    int lane = t & 63, wave = t >> 6;
    int s = lane & 15, dl = lane >> 4;
    int d = blockIdx.x*16 + wave*4 + dl;
    float Aa = -__expf(A_log[d*DST + s]);
    float dp = Dpv[d];
    const float4* dtp = (const float4*)(dtT + ((size_t)b*DIN + d)*LQ + c*CLEN);
    const float4* up  = (const float4*)(uT  + ((size_t)b*DIN + d)*LQ + c*CLEN);
    const float4* Bp  = (const float4*)(BT  + ((size_t)b*DST + s)*LQ + c*CLEN);
    const float4* Cp  = (const float4*)(CT  + ((size_t)b*DST + s)*LQ + c*CLEN);
    float4* yp = (float4*)(yT + ((size_t)b*DIN + d)*LQ + c*CLEN);
    float hh = H[(((size_t)b*CHK + c)*DIN + d)*DST + s];
    float4 dt4 = dtp[0], u4 = up[0], B4 = Bp[0], C4 = Cp[0];
    for(int g=0; g<CLEN/4; g++){
        float4 nd, nu, nB, nC;
        if(g < CLEN/4 - 1){ nd = dtp[g+1]; nu = up[g+1]; nB = Bp[g+1]; nC = Cp[g+1]; }
        float dtv[4] = {dt4.x,dt4.y,dt4.z,dt4.w};
        float uv[4]  = {u4.x,u4.y,u4.z,u4.w};
        float Bv[4]  = {B4.x,B4.y,B4.z,B4.w};
        float Cv[4]  = {C4.x,C4.y,C4.z,C4.w};
        float yv[4];
        #pragma unroll
        for(int j=0;j<4;j++){
            float dA = __expf(dtv[j]*Aa);
            hh = hh*dA + dtv[j]*uv[j]*Bv[j];
            float py = hh*Cv[j];
            py += __shfl_xor(py,1,16);
            py += __shfl_xor(py,2,16);
            py += __shfl_xor(py,4,16);
            py += __shfl_xor(py,8,16);
            yv[j] = py + uv[j]*dp;
        }
        if(s==0) yp[g] = make_float4(yv[0],yv[1],yv[2],yv[3]);
        dt4=nd; u4=nu; B4=nB; C4=nC;
    }
}

// ---------------- gate: yg[m,d] = yT[b,d,l] * silu(z[m,d]) (transpose via LDS) ----------------
__global__ __launch_bounds__(256) void k_gate(const float* __restrict__ yT,
                                              const float* __restrict__ xz,
                                              float* __restrict__ yg){
    __shared__ float Tt[64][65];
    int lt0 = blockIdx.x*64, d0 = blockIdx.y*64, b = blockIdx.z;
    int t = threadIdx.x;
    int r = t >> 6, c = t & 63;
    #pragma unroll
    for(int i=0;i<16;i++){
        int d = r + i*4;
        Tt[d][c] = yT[((size_t)(b*DIN + d0 + d))*LQ + lt0 + c];
    }
    __syncthreads();
    #pragma unroll
    for(int i=0;i<16;i++){
        int l = r + i*4;
        size_t m = (size_t)b*LQ + lt0 + l;
        float z = xz[m*1024 + 512 + d0 + c];
        yg[m*DIN + d0 + c] = Tt[c][l] * fsilu(z);
    }
}

extern "C" void kernel_launch(void* const* d_in, const int* in_sizes, int n_in,
                              void* d_out, int out_size, void* d_ws, size_t ws_size,
                              hipStream_t stream){
    (void)in_sizes; (void)n_in; (void)out_size; (void)ws_size;
    const float* x        = (const float*)d_in[0];
    const float* ln_g     = (const float*)d_in[1];
    const float* ln_b     = (const float*)d_in[2];
    const float* in_w     = (const float*)d_in[3];
    const float* conv_w   = (const float*)d_in[4];
    const float* conv_b   = (const float*)d_in[5];
    const float* xproj_w  = (const float*)d_in[6];
    const float* dtproj_w = (const float*)d_in[7];
    const float* dtproj_b = (const float*)d_in[8];
    const float* A_log    = (const float*)d_in[9];
    const float* Dp       = (const float*)d_in[10];
    const float* out_w    = (const float*)d_in[11];
    float* h = (float*)d_out;
    float* ws = (float*)d_ws;

    // workspace layout (floats) — total 46,137,344 (same as R1 footprint)
    float* xz      = ws;                          // 16,777,216
    float* scratch = xz + (size_t)MT*1024;        //  4,194,304 region
    float* hnorm   = scratch;                     //  (aliases dbc/... temporally)
    float* dbc     = scratch;                     //    786,432
    float* BT      = scratch + 786432;            //    262,144
    float* CT      = BT + 262144;                 //    262,144
    float* Sbuf    = CT + 262144;                 //  1,048,576  (B*CHK*DIN*DST)
    float* Hbuf    = Sbuf + 1048576;              //  1,048,576
    float* sumdt   = Hbuf + 1048576;              //     65,536
    float* uT      = scratch + 4194304;           //  8,388,608
    float* dtT     = uT + 8388608;                //  8,388,608 (reused as yg)
    float* yg      = dtT;
    float* yT      = dtT + 8388608;               //  8,388,608

    k_copy<<<(MT*DMD/4 + 255)/256, 256, 0, stream>>>((const float4*)x, (float4*)h, MT*DMD/4);

    for(int li=0; li<3; li++){
        const float* Al = A_log + (size_t)li*DIN*DST;

        k_ln<<<MT/4, 256, 0, stream>>>(h, ln_g, ln_b, hnorm);

        dim3 g1(MT/BM, 1024/BN);
        k_gemm<<<g1, 256, 0, stream>>>(hnorm, in_w + (size_t)li*1024*DMD, xz,
                                       1024, DMD, 1024, 0, 0);

        dim3 gc(LQ/64, DIN/64, NB);
        k_conv<<<gc, 256, 0, stream>>>(xz, conv_w + (size_t)li*DIN*4, conv_b + (size_t)li*DIN, uT);

        dim3 g2(MT/BM, 1);
        k_gemm<<<g2, 256, 0, stream>>>(uT, xproj_w + (size_t)li*48*DIN, dbc,
                                       48, DIN, 48, 1, 0);

        dim3 gdt(LQ/256, DIN, NB);
        k_dt<<<gdt, 256, 0, stream>>>(dbc, dtproj_w + (size_t)li*DIN*16, dtproj_b + (size_t)li*DIN, dtT);

        dim3 gbc(LQ/256, NB);
        k_bct<<<gbc, 256, 0, stream>>>(dbc, BT, CT);

        dim3 gs1(DIN/16, CHK, NB);
        k_scan1<<<gs1, 256, 0, stream>>>(dtT, uT, BT, Al, Sbuf, sumdt);

        k_scan2<<<(NB*DIN*DST)/256, 256, 0, stream>>>(Sbuf, sumdt, Al, Hbuf);

        dim3 gs3(DIN/16, CHK, NB);
        k_scan3<<<gs3, 256, 0, stream>>>(dtT, uT, BT, CT, Al, Dp + (size_t)li*DIN, Hbuf, yT);

        dim3 gg(LQ/64, DIN/64, NB);
        k_gate<<<gg, 256, 0, stream>>>(yT, xz, yg);

        dim3 g3(MT/BM, DMD/BN);
        k_gemm<<<g3, 256, 0, stream>>>(yg, out_w + (size_t)li*DMD*DIN, h,
                                       DMD, DIN, DMD, 0, 1);
    }
}

// Round 3
// 845.421 us; speedup vs baseline: 2.1828x; 2.1828x over previous
//
#include <hip/hip_runtime.h>

#define NB   8
#define LQ   2048
#define DMD  256
#define DIN  512
#define DST  16
#define MT   (NB*LQ)   // 16384 tokens
#define CHK  64        // scan chunks
#define CLEN (LQ/CHK)  // 32 steps per chunk

#define BM 128
#define BN 64
#define BK 16

typedef __attribute__((ext_vector_type(8))) short bf16x8;
typedef __attribute__((ext_vector_type(4))) float f32x4;

__device__ __forceinline__ float fsilu(float x){ return x / (1.f + __expf(-x)); }
__device__ __forceinline__ unsigned short f2bf(float x){
    unsigned int u = __float_as_uint(x);
    u += 0x7FFFu + ((u >> 16) & 1u);          // RNE
    return (unsigned short)(u >> 16);
}

// ---------------- h = x ----------------
__global__ void k_copy(const float4* __restrict__ src, float4* __restrict__ dst, int n4){
    int i = blockIdx.x*256 + threadIdx.x;
    if(i < n4) dst[i] = src[i];
}

// ---------------- f32 -> bf16 cast (weights) ----------------
__global__ void k_cast(const float* __restrict__ src, unsigned short* __restrict__ dst, int n){
    int i = (blockIdx.x*256 + threadIdx.x)*4;
    if(i < n){
        float4 v = *(const float4*)(src + i);
        ushort4 o; o.x=f2bf(v.x); o.y=f2bf(v.y); o.z=f2bf(v.z); o.w=f2bf(v.w);
        *(ushort4*)(dst + i) = o;
    }
}

// ---------------- layernorm, bf16 output ----------------
__global__ __launch_bounds__(256) void k_ln(const float* __restrict__ h,
                                            const float* __restrict__ g,
                                            const float* __restrict__ b,
                                            unsigned short* __restrict__ out){
    int wave = threadIdx.x >> 6, lane = threadIdx.x & 63;
    int m = blockIdx.x*4 + wave;
    const float* row = h + (size_t)m*DMD;
    float4 v = *(const float4*)(row + lane*4);
    float s  = v.x+v.y+v.z+v.w;
    float sq = v.x*v.x+v.y*v.y+v.z*v.z+v.w*v.w;
    #pragma unroll
    for(int o=32;o;o>>=1){ s += __shfl_xor(s,o,64); sq += __shfl_xor(sq,o,64); }
    float mu  = s*(1.f/DMD);
    float var = sq*(1.f/DMD) - mu*mu;
    float rs  = rsqrtf(var + 1e-5f);
    float4 gg = *(const float4*)(g + lane*4);
    float4 bb = *(const float4*)(b + lane*4);
    ushort4 o4;
    o4.x = f2bf((v.x-mu)*rs*gg.x+bb.x); o4.y = f2bf((v.y-mu)*rs*gg.y+bb.y);
    o4.z = f2bf((v.z-mu)*rs*gg.z+bb.z); o4.w = f2bf((v.w-mu)*rs*gg.w+bb.w);
    *(ushort4*)(out + (size_t)m*DMD + lane*4) = o4;
}

// ---------------- bf16 MFMA GEMM: C[m,n] = sum_k A[m,k]*B[n,k] (+C if accum) ----------------
// A [M,K] bf16 row-major, B [N,K] bf16 row-major, C f32 [M,ldc]. M%128==0, N%128==0, K%32==0.
__global__ __launch_bounds__(256,2) void k_gemm_bf16(const unsigned short* __restrict__ A,
                                                     const unsigned short* __restrict__ B,
                                                     float* __restrict__ C,
                                                     int K, int ldc, int accum){
    __shared__ unsigned short As[128*40];
    __shared__ unsigned short Bs[128*40];
    const int t = threadIdx.x;
    const int m0 = blockIdx.x*128, n0 = blockIdx.y*128;
    const int lane = t & 63, wave = t >> 6;
    const int wm = (wave & 1)*64, wn = (wave >> 1)*64;
    const int fr = lane & 15, quad = lane >> 4;
    f32x4 acc[4][4];
    #pragma unroll
    for(int i=0;i<4;i++)
        #pragma unroll
        for(int j=0;j<4;j++) acc[i][j] = (f32x4){0.f,0.f,0.f,0.f};

    const int lrow = t >> 1, lhalf = (t & 1)*16;
    const unsigned short* Ap = A + (size_t)(m0 + lrow)*K + lhalf;
    const unsigned short* Bp = B + (size_t)(n0 + lrow)*K + lhalf;

    for(int k0 = 0; k0 < K; k0 += 32){
        float4 a0 = *(const float4*)(Ap + k0);
        float4 a1 = *(const float4*)(Ap + k0 + 8);
        float4 b0 = *(const float4*)(Bp + k0);
        float4 b1 = *(const float4*)(Bp + k0 + 8);
        *(float4*)(As + lrow*40 + lhalf)     = a0;
        *(float4*)(As + lrow*40 + lhalf + 8) = a1;
        *(float4*)(Bs + lrow*40 + lhalf)     = b0;
        *(float4*)(Bs + lrow*40 + lhalf + 8) = b1;
        __syncthreads();
        bf16x8 af[4], bfr[4];
        #pragma unroll
        for(int i=0;i<4;i++){
            af[i]  = *(const bf16x8*)(As + (wm + i*16 + fr)*40 + quad*8);
            bfr[i] = *(const bf16x8*)(Bs + (wn + i*16 + fr)*40 + quad*8);
        }
        #pragma unroll
        for(int i=0;i<4;i++)
            #pragma unroll
            for(int j=0;j<4;j++)
                acc[i][j] = __builtin_amdgcn_mfma_f32_16x16x32_bf16(af[i], bfr[j], acc[i][j], 0,0,0);
        __syncthreads();
    }
    #pragma unroll
    for(int i=0;i<4;i++){
        #pragma unroll
        for(int j=0;j<4;j++){
            int nn = n0 + wn + j*16 + fr;
            #pragma unroll
            for(int r=0;r<4;r++){
                int mm = m0 + wm + i*16 + quad*4 + r;
                float v = acc[i][j][r];
                float* cp = C + (size_t)mm*ldc + nn;
                if(accum) v += *cp;
                *cp = v;
            }
        }
    }
}

// ---------------- f32 GEMM (x-proj only): C[m,n] = sum_k A[m,k]*Bw[n,k] ----------------
__global__ __launch_bounds__(256,2) void k_gemm(const float* __restrict__ A,
                                                const float* __restrict__ Bw,
                                                float* __restrict__ C,
                                                int N, int K, int ldc){
    __shared__ float As[BK][BM+4];
    __shared__ float Bs[BK][BN+4];
    const int t  = threadIdx.x;
    const int m0 = blockIdx.x * BM;
    const int n0 = blockIdx.y * BN;
    const int tx = t & 15, ty = t >> 4;
    float acc[8][4];
    #pragma unroll
    for(int i=0;i<8;i++)
        #pragma unroll
        for(int j=0;j<4;j++) acc[i][j]=0.f;

    const float* Abase = A + (size_t)m0*K;
    for(int k0=0; k0<K; k0+=BK){
        {
            int tk = t & 15, tr = t >> 4;
            #pragma unroll
            for(int i=0;i<8;i++)
                As[tk][tr+i*16] = Abase[(size_t)(tr+i*16)*K + k0 + tk];
        }
        {
            int tk = t & 15, tn = t >> 4;
            #pragma unroll
            for(int i=0;i<4;i++){
                int n = tn + i*16;
                Bs[tk][n] = (n0+n < N) ? Bw[(size_t)(n0+n)*K + k0+tk] : 0.f;
            }
        }
        __syncthreads();
        #pragma unroll
        for(int k=0;k<BK;k++){
            float a[8], bv[4];
            *(float4*)&a[0] = *(const float4*)&As[k][ty*8];
            *(float4*)&a[4] = *(const float4*)&As[k][ty*8+4];
            *(float4*)&bv[0] = *(const float4*)&Bs[k][tx*4];
            #pragma unroll
            for(int i=0;i<8;i++)
                #pragma unroll
                for(int j=0;j<4;j++) acc[i][j] += a[i]*bv[j];
        }
        __syncthreads();
    }
    int n = n0 + tx*4;
    if(n < N){
        #pragma unroll
        for(int i=0;i<8;i++)
            *(float4*)(C + (size_t)(m0+ty*8+i)*ldc + n) =
                make_float4(acc[i][0],acc[i][1],acc[i][2],acc[i][3]);
    }
}

// ---------------- causal depthwise conv(4) + SiLU, row-major output u[m,d] ----------------
__global__ __launch_bounds__(256) void k_conv(const float* __restrict__ xz,
                                              const float* __restrict__ cw,
                                              const float* __restrict__ cb,
                                              float* __restrict__ u){
    __shared__ float us[67][64];
    int lt0 = blockIdx.x*64, d0 = blockIdx.y*64, b = blockIdx.z;
    int t = threadIdx.x;
    for(int idx=t; idx<67*64; idx+=256){
        int r = idx >> 6, cc = idx & 63;
        int l = lt0 - 3 + r;
        us[r][cc] = (l >= 0) ? xz[((size_t)(b*LQ + l))*1024 + d0 + cc] : 0.f;
    }
    __syncthreads();
    int cc = t & 63, rg = t >> 6;
    int d = d0 + cc;
    float w0=cw[d*4+0], w1=cw[d*4+1], w2=cw[d*4+2], w3=cw[d*4+3];
    float bias = cb[d];
    #pragma unroll
    for(int i=0;i<16;i++){
        int l = rg*16 + i;
        float a = bias + w0*us[l][cc] + w1*us[l+1][cc] + w2*us[l+2][cc] + w3*us[l+3][cc];
        u[((size_t)(b*LQ + lt0 + l))*DIN + d] = fsilu(a);
    }
}

// ---------------- dt = softplus(dbc[:, :16] @ dtw^T + dtb) -> dtM[m,d] ----------------
__global__ __launch_bounds__(256) void k_dt(const float* __restrict__ dbc,
                                            const float* __restrict__ w,
                                            const float* __restrict__ bias,
                                            float* __restrict__ dtM){
    __shared__ float Ds[32][16];
    int m0 = blockIdx.x*32;
    int t = threadIdx.x;
    if(t < 128){
        int token = t >> 2, part = t & 3;
        *(float4*)(&Ds[token][part*4]) = *(const float4*)(dbc + (size_t)(m0+token)*48 + part*4);
    }
    float wreg[2][16], bv[2];
    #pragma unroll
    for(int hh=0; hh<2; hh++){
        int d = t + hh*256;
        bv[hh] = bias[d];
        #pragma unroll
        for(int k=0;k<16;k+=4){
            float4 v = *(const float4*)(w + d*16 + k);
            wreg[hh][k]=v.x; wreg[hh][k+1]=v.y; wreg[hh][k+2]=v.z; wreg[hh][k+3]=v.w;
        }
    }
    __syncthreads();
    for(int tok=0; tok<32; tok++){
        #pragma unroll
        for(int hh=0;hh<2;hh++){
            float acc = bv[hh];
            #pragma unroll
            for(int k=0;k<16;k++) acc += Ds[tok][k]*wreg[hh][k];
            float sp = (acc > 20.f) ? acc : log1pf(__expf(acc));
            dtM[(size_t)(m0+tok)*DIN + t + hh*256] = sp;
        }
    }
}

// ---------------- scan phase 1: per-chunk local scan (h0=0), 16 states in registers ----
__global__ __launch_bounds__(256) void k_scan1(const float* __restrict__ dtM,
                                               const float* __restrict__ u,
                                               const float* __restrict__ dbc,
                                               const float* __restrict__ A_log,
                                               float* __restrict__ S,
                                               float* __restrict__ sumdt){
    int b = blockIdx.y;
    int c = blockIdx.x >> 1;
    int d0 = (blockIdx.x & 1)*256;
    int t = threadIdx.x;
    int d = d0 + t;
    int m0 = b*LQ + c*CLEN;
    __shared__ float Bsh[CLEN][20];
    if(t < 128){
        int token = t >> 2, part = t & 3;
        *(float4*)(&Bsh[token][part*4]) = *(const float4*)(dbc + (size_t)(m0+token)*48 + 16 + part*4);
    }
    float Aa[16], hs[16];
    #pragma unroll
    for(int s=0;s<16;s++){ Aa[s] = -__expf(A_log[d*16+s]); hs[s] = 0.f; }
    float sdt = 0.f;
    __syncthreads();
    float dt_n = dtM[(size_t)m0*DIN + d];
    float u_n  = u[(size_t)m0*DIN + d];
    for(int tt=0; tt<CLEN; tt++){
        float dtv = dt_n, uv = u_n;
        if(tt+1 < CLEN){
            dt_n = dtM[(size_t)(m0+tt+1)*DIN + d];
            u_n  = u[(size_t)(m0+tt+1)*DIN + d];
        }
        float du = dtv*uv;
        sdt += dtv;
        #pragma unroll
        for(int s=0;s<16;s++)
            hs[s] = hs[s]*__expf(dtv*Aa[s]) + du*Bsh[tt][s];
    }
    float* Sp = S + (((size_t)b*CHK + c)*DIN + d)*16;
    #pragma unroll
    for(int q=0;q<4;q++)
        *(float4*)(Sp + q*4) = make_float4(hs[q*4],hs[q*4+1],hs[q*4+2],hs[q*4+3]);
    sumdt[((size_t)b*CHK + c)*DIN + d] = sdt;
}

// ---------------- scan phase 2: serial combine over chunks -> H ----------------
__global__ __launch_bounds__(256) void k_scan2(const float* __restrict__ S,
                                               const float* __restrict__ sumdt,
                                               const float* __restrict__ A_log,
                                               float* __restrict__ H){
    int idx = blockIdx.x*256 + threadIdx.x;   // (b, d, s)
    int s = idx & 15;
    int d = (idx >> 4) & (DIN-1);
    int b = idx >> 13;
    float Aa = -__expf(A_log[d*DST + s]);
    float hh = 0.f;
    for(int c=0; c<CHK; c++){
        size_t o = (((size_t)b*CHK + c)*DIN + d)*DST + s;
        H[o] = hh;
        float P = __expf(Aa * sumdt[((size_t)b*CHK + c)*DIN + d]);
        hh = hh*P + S[o];
    }
}

// ---------------- scan phase 3 + gate + bf16 cast: yg[m,d] (bf16) ----------------
__global__ __launch_bounds__(256) void k_scan3(const float* __restrict__ dtM,
                                               const float* __restrict__ u,
                                               const float* __restrict__ dbc,
                                               const float* __restrict__ xz,
                                               const float* __restrict__ A_log,
                                               const float* __restrict__ Dpv,
                                               const float* __restrict__ H,
                                               unsigned short* __restrict__ yg){
    int b = blockIdx.y;
    int c = blockIdx.x >> 1;
    int d0 = (blockIdx.x & 1)*256;
    int t = threadIdx.x;
    int d = d0 + t;
    int m0 = b*LQ + c*CLEN;
    __shared__ float BCs[CLEN][36];   // [token][0:16]=B, [16:32]=C
    {
        int token = t >> 3, part = t & 7;
        *(float4*)(&BCs[token][part*4]) = *(const float4*)(dbc + (size_t)(m0+token)*48 + 16 + part*4);
    }
    float Aa[16], hs[16];
    #pragma unroll
    for(int s=0;s<16;s++) Aa[s] = -__expf(A_log[d*16+s]);
    const float* Hp = H + (((size_t)b*CHK + c)*DIN + d)*16;
    #pragma unroll
    for(int q=0;q<4;q++){
        float4 v = *(const float4*)(Hp + q*4);
        hs[q*4]=v.x; hs[q*4+1]=v.y; hs[q*4+2]=v.z; hs[q*4+3]=v.w;
    }
    float dp = Dpv[d];
    __syncthreads();
    float dt_n = dtM[(size_t)m0*DIN + d];
    float u_n  = u[(size_t)m0*DIN + d];
    for(int tt=0; tt<CLEN; tt++){
        float dtv = dt_n, uv = u_n;
        if(tt+1 < CLEN){
            dt_n = dtM[(size_t)(m0+tt+1)*DIN + d];
            u_n  = u[(size_t)(m0+tt+1)*DIN + d];
        }
        float du = dtv*uv;
        float y = 0.f;
        #pragma unroll
        for(int s=0;s<16;s++){
            hs[s] = hs[s]*__expf(dtv*Aa[s]) + du*BCs[tt][s];
            y += hs[s]*BCs[tt][16+s];
        }
        y += uv*dp;
        float z = xz[(size_t)(m0+tt)*1024 + 512 + d];
        yg[(size_t)(m0+tt)*DIN + d] = f2bf(y * fsilu(z));
    }
}

extern "C" void kernel_launch(void* const* d_in, const int* in_sizes, int n_in,
                              void* d_out, int out_size, void* d_ws, size_t ws_size,
                              hipStream_t stream){
    (void)in_sizes; (void)n_in; (void)out_size; (void)ws_size;
    const float* x        = (const float*)d_in[0];
    const float* ln_g     = (const float*)d_in[1];
    const float* ln_b     = (const float*)d_in[2];
    const float* in_w     = (const float*)d_in[3];
    const float* conv_w   = (const float*)d_in[4];
    const float* conv_b   = (const float*)d_in[5];
    const float* xproj_w  = (const float*)d_in[6];
    const float* dtproj_w = (const float*)d_in[7];
    const float* dtproj_b = (const float*)d_in[8];
    const float* A_log    = (const float*)d_in[9];
    const float* Dp       = (const float*)d_in[10];
    const float* out_w    = (const float*)d_in[11];
    float* h = (float*)d_out;
    float* ws = (float*)d_ws;

    // workspace layout (float offsets); total 43,581,440 floats (~174 MB)
    float* xz   = ws;                              // 16,777,216
    float* u    = ws + 16777216;                   //  8,388,608
    float* dtM  = ws + 25165824;                   //  8,388,608
    float* dbc  = ws + 33554432;                   //    786,432
    float* R1   = ws + 34340864;                   //  4,194,304 (hn_bf / S / yg_bf, disjoint lifetimes)
    float* Hbuf = ws + 38535168;                   //  4,194,304
    float* sumdt= ws + 42729472;                   //    262,144
    unsigned short* inw_bf  = (unsigned short*)(ws + 42991616);  // 786,432 bf16
    unsigned short* outw_bf = (unsigned short*)(ws + 43384832);  // 393,216 bf16
    unsigned short* hn_bf = (unsigned short*)R1;
    unsigned short* yg_bf = (unsigned short*)R1;
    float* Sbuf = R1;

    k_cast<<<768, 256, 0, stream>>>(in_w,  inw_bf,  3*1024*DMD);
    k_cast<<<384, 256, 0, stream>>>(out_w, outw_bf, 3*DMD*DIN);
    k_copy<<<(MT*DMD/4 + 255)/256, 256, 0, stream>>>((const float4*)x, (float4*)h, MT*DMD/4);

    for(int li=0; li<3; li++){
        const float* Al = A_log + (size_t)li*DIN*DST;

        k_ln<<<MT/4, 256, 0, stream>>>(h, ln_g, ln_b, hn_bf);

        dim3 g1(MT/128, 1024/128);
        k_gemm_bf16<<<g1, 256, 0, stream>>>(hn_bf, inw_bf + (size_t)li*1024*DMD, xz,
                                            DMD, 1024, 0);

        dim3 gc(LQ/64, DIN/64, NB);
        k_conv<<<gc, 256, 0, stream>>>(xz, conv_w + (size_t)li*DIN*4, conv_b + (size_t)li*DIN, u);

        dim3 g2(MT/BM, 1);
        k_gemm<<<g2, 256, 0, stream>>>(u, xproj_w + (size_t)li*48*DIN, dbc, 48, DIN, 48);

        k_dt<<<MT/32, 256, 0, stream>>>(dbc, dtproj_w + (size_t)li*DIN*16,
                                        dtproj_b + (size_t)li*DIN, dtM);

        dim3 gs(2*CHK, NB);
        k_scan1<<<gs, 256, 0, stream>>>(dtM, u, dbc, Al, Sbuf, sumdt);

        k_scan2<<<(NB*DIN*DST)/256, 256, 0, stream>>>(Sbuf, sumdt, Al, Hbuf);

        k_scan3<<<gs, 256, 0, stream>>>(dtM, u, dbc, xz, Al, Dp + (size_t)li*DIN, Hbuf, yg_bf);

        dim3 g3(MT/128, DMD/128);
        k_gemm_bf16<<<g3, 256, 0, stream>>>(yg_bf, outw_bf + (size_t)li*DMD*DIN, h,
                                            DIN, DMD, 1);
    }
}

// Round 4
// 681.073 us; speedup vs baseline: 2.7095x; 1.2413x over previous
//
#include <hip/hip_runtime.h>

#define NB   8
#define LQ   2048
#define DMD  256
#define DIN  512
#define DST  16
#define MT   (NB*LQ)   // 16384 tokens
#define CHK  64        // scan chunks
#define CLEN (LQ/CHK)  // 32 steps per chunk

typedef __attribute__((ext_vector_type(8))) short bf16x8;
typedef __attribute__((ext_vector_type(4))) float f32x4;

__device__ __forceinline__ float fsilu(float x){ return x / (1.f + __expf(-x)); }
__device__ __forceinline__ unsigned short f2bf(float x){
    unsigned int u = __float_as_uint(x);
    u += 0x7FFFu + ((u >> 16) & 1u);          // RNE
    return (unsigned short)(u >> 16);
}

// ---------------- h = x ----------------
__global__ void k_copy(const float4* __restrict__ src, float4* __restrict__ dst, int n4){
    int i = blockIdx.x*256 + threadIdx.x;
    if(i < n4) dst[i] = src[i];
}

// ---------------- f32 -> bf16 cast (weights) ----------------
__global__ void k_cast(const float* __restrict__ src, unsigned short* __restrict__ dst, int n){
    int i = (blockIdx.x*256 + threadIdx.x)*4;
    if(i < n){
        float4 v = *(const float4*)(src + i);
        ushort4 o; o.x=f2bf(v.x); o.y=f2bf(v.y); o.z=f2bf(v.z); o.w=f2bf(v.w);
        *(ushort4*)(dst + i) = o;
    }
}

// ---------------- layernorm, bf16 output ----------------
__global__ __launch_bounds__(256) void k_ln(const float* __restrict__ h,
                                            const float* __restrict__ g,
                                            const float* __restrict__ b,
                                            unsigned short* __restrict__ out){
    int wave = threadIdx.x >> 6, lane = threadIdx.x & 63;
    int m = blockIdx.x*4 + wave;
    const float* row = h + (size_t)m*DMD;
    float4 v = *(const float4*)(row + lane*4);
    float s  = v.x+v.y+v.z+v.w;
    float sq = v.x*v.x+v.y*v.y+v.z*v.z+v.w*v.w;
    #pragma unroll
    for(int o=32;o;o>>=1){ s += __shfl_xor(s,o,64); sq += __shfl_xor(sq,o,64); }
    float mu  = s*(1.f/DMD);
    float var = sq*(1.f/DMD) - mu*mu;
    float rs  = rsqrtf(var + 1e-5f);
    float4 gg = *(const float4*)(g + lane*4);
    float4 bb = *(const float4*)(b + lane*4);
    ushort4 o4;
    o4.x = f2bf((v.x-mu)*rs*gg.x+bb.x); o4.y = f2bf((v.y-mu)*rs*gg.y+bb.y);
    o4.z = f2bf((v.z-mu)*rs*gg.z+bb.z); o4.w = f2bf((v.w-mu)*rs*gg.w+bb.w);
    *(ushort4*)(out + (size_t)m*DMD + lane*4) = o4;
}

// ---------------- bf16 MFMA GEMM: C[m,n] = sum_k A[m,k]*B[n,k] (+C if accum) ----------------
__global__ __launch_bounds__(256,2) void k_gemm_bf16(const unsigned short* __restrict__ A,
                                                     const unsigned short* __restrict__ B,
                                                     float* __restrict__ C,
                                                     int K, int ldc, int accum){
    __shared__ unsigned short As[128*40];
    __shared__ unsigned short Bs[128*40];
    const int t = threadIdx.x;
    const int m0 = blockIdx.x*128, n0 = blockIdx.y*128;
    const int lane = t & 63, wave = t >> 6;
    const int wm = (wave & 1)*64, wn = (wave >> 1)*64;
    const int fr = lane & 15, quad = lane >> 4;
    f32x4 acc[4][4];
    #pragma unroll
    for(int i=0;i<4;i++)
        #pragma unroll
        for(int j=0;j<4;j++) acc[i][j] = (f32x4){0.f,0.f,0.f,0.f};

    const int lrow = t >> 1, lhalf = (t & 1)*16;
    const unsigned short* Ap = A + (size_t)(m0 + lrow)*K + lhalf;
    const unsigned short* Bp = B + (size_t)(n0 + lrow)*K + lhalf;

    for(int k0 = 0; k0 < K; k0 += 32){
        float4 a0 = *(const float4*)(Ap + k0);
        float4 a1 = *(const float4*)(Ap + k0 + 8);
        float4 b0 = *(const float4*)(Bp + k0);
        float4 b1 = *(const float4*)(Bp + k0 + 8);
        *(float4*)(As + lrow*40 + lhalf)     = a0;
        *(float4*)(As + lrow*40 + lhalf + 8) = a1;
        *(float4*)(Bs + lrow*40 + lhalf)     = b0;
        *(float4*)(Bs + lrow*40 + lhalf + 8) = b1;
        __syncthreads();
        bf16x8 af[4], bfr[4];
        #pragma unroll
        for(int i=0;i<4;i++){
            af[i]  = *(const bf16x8*)(As + (wm + i*16 + fr)*40 + quad*8);
            bfr[i] = *(const bf16x8*)(Bs + (wn + i*16 + fr)*40 + quad*8);
        }
        #pragma unroll
        for(int i=0;i<4;i++)
            #pragma unroll
            for(int j=0;j<4;j++)
                acc[i][j] = __builtin_amdgcn_mfma_f32_16x16x32_bf16(af[i], bfr[j], acc[i][j], 0,0,0);
        __syncthreads();
    }
    #pragma unroll
    for(int i=0;i<4;i++){
        #pragma unroll
        for(int j=0;j<4;j++){
            int nn = n0 + wn + j*16 + fr;
            #pragma unroll
            for(int r=0;r<4;r++){
                int mm = m0 + wm + i*16 + quad*4 + r;
                float v = acc[i][j][r];
                float* cp = C + (size_t)mm*ldc + nn;
                if(accum) v += *cp;
                *cp = v;
            }
        }
    }
}

// ---------------- skinny x-proj GEMM: dbc[m,0:48] = sum_k u_bf[m,k]*xw_bf[n,k] ----------------
// M-tile 64 (grid 256 blocks). B-panel (48x512) staged once in LDS; K-loop barrier-free:
// A-fragments loaded straight from global (16B/lane), 3 MFMAs per k-step.
__global__ __launch_bounds__(256,2) void k_xproj(const unsigned short* __restrict__ A,
                                                 const unsigned short* __restrict__ B,
                                                 float* __restrict__ C){
    __shared__ unsigned short Bs[48*520];
    const int t = threadIdx.x;
    const int m0 = blockIdx.x*64;
    const int lane = t & 63, wave = t >> 6;
    const int fr = lane & 15, quad = lane >> 4;
    // stage B: 48 rows x 64 slots of 8 shorts
    for(int s=t; s<3072; s+=256){
        int row = s >> 6, sl = s & 63;
        *(float4*)(Bs + row*520 + sl*8) = *(const float4*)(B + (size_t)row*512 + sl*8);
    }
    __syncthreads();
    f32x4 acc[3];
    #pragma unroll
    for(int j=0;j<3;j++) acc[j] = (f32x4){0.f,0.f,0.f,0.f};
    const unsigned short* Ap = A + (size_t)(m0 + wave*16 + fr)*512 + quad*8;
    #pragma unroll 4
    for(int k0=0; k0<512; k0+=32){
        bf16x8 af = *(const bf16x8*)(Ap + k0);
        #pragma unroll
        for(int j=0;j<3;j++){
            bf16x8 bfr = *(const bf16x8*)(Bs + (j*16 + fr)*520 + quad*8 + k0);
            acc[j] = __builtin_amdgcn_mfma_f32_16x16x32_bf16(af, bfr, acc[j], 0,0,0);
        }
    }
    #pragma unroll
    for(int j=0;j<3;j++){
        #pragma unroll
        for(int r=0;r<4;r++){
            int mm = m0 + wave*16 + quad*4 + r;
            C[(size_t)mm*48 + j*16 + fr] = acc[j][r];
        }
    }
}

// ---------------- causal depthwise conv(4) + SiLU, u[m,d] f32 + u_bf[m,d] bf16 ----------------
__global__ __launch_bounds__(256) void k_conv(const float* __restrict__ xz,
                                              const float* __restrict__ cw,
                                              const float* __restrict__ cb,
                                              float* __restrict__ u,
                                              unsigned short* __restrict__ ub){
    __shared__ float us[67][64];
    int lt0 = blockIdx.x*64, d0 = blockIdx.y*64, b = blockIdx.z;
    int t = threadIdx.x;
    for(int idx=t; idx<67*64; idx+=256){
        int r = idx >> 6, cc = idx & 63;
        int l = lt0 - 3 + r;
        us[r][cc] = (l >= 0) ? xz[((size_t)(b*LQ + l))*1024 + d0 + cc] : 0.f;
    }
    __syncthreads();
    int cc = t & 63, rg = t >> 6;
    int d = d0 + cc;
    float w0=cw[d*4+0], w1=cw[d*4+1], w2=cw[d*4+2], w3=cw[d*4+3];
    float bias = cb[d];
    #pragma unroll
    for(int i=0;i<16;i++){
        int l = rg*16 + i;
        float a = bias + w0*us[l][cc] + w1*us[l+1][cc] + w2*us[l+2][cc] + w3*us[l+3][cc];
        float v = fsilu(a);
        size_t o = ((size_t)(b*LQ + lt0 + l))*DIN + d;
        u[o] = v;
        ub[o] = f2bf(v);
    }
}

// ---------------- dt = softplus(dbc[:, :16] @ dtw^T + dtb) -> dtM[m,d] ----------------
__global__ __launch_bounds__(256) void k_dt(const float* __restrict__ dbc,
                                            const float* __restrict__ w,
                                            const float* __restrict__ bias,
                                            float* __restrict__ dtM){
    __shared__ float Ds[32][16];
    int m0 = blockIdx.x*32;
    int t = threadIdx.x;
    if(t < 128){
        int token = t >> 2, part = t & 3;
        *(float4*)(&Ds[token][part*4]) = *(const float4*)(dbc + (size_t)(m0+token)*48 + part*4);
    }
    float wreg[2][16], bv[2];
    #pragma unroll
    for(int hh=0; hh<2; hh++){
        int d = t + hh*256;
        bv[hh] = bias[d];
        #pragma unroll
        for(int k=0;k<16;k+=4){
            float4 v = *(const float4*)(w + d*16 + k);
            wreg[hh][k]=v.x; wreg[hh][k+1]=v.y; wreg[hh][k+2]=v.z; wreg[hh][k+3]=v.w;
        }
    }
    __syncthreads();
    for(int tok=0; tok<32; tok++){
        #pragma unroll
        for(int hh=0;hh<2;hh++){
            float acc = bv[hh];
            #pragma unroll
            for(int k=0;k<16;k++) acc += Ds[tok][k]*wreg[hh][k];
            float sp = (acc > 20.f) ? acc : log1pf(__expf(acc));
            dtM[(size_t)(m0+tok)*DIN + t + hh*256] = sp;
        }
    }
}

// ---------------- scan phase 1: per-chunk local scan (h0=0), 16 states in registers ----
__global__ __launch_bounds__(256) void k_scan1(const float* __restrict__ dtM,
                                               const float* __restrict__ u,
                                               const float* __restrict__ dbc,
                                               const float* __restrict__ A_log,
                                               float* __restrict__ S,
                                               float* __restrict__ sumdt){
    int b = blockIdx.y;
    int c = blockIdx.x >> 1;
    int d0 = (blockIdx.x & 1)*256;
    int t = threadIdx.x;
    int d = d0 + t;
    int m0 = b*LQ + c*CLEN;
    __shared__ float Bsh[CLEN][20];
    if(t < 128){
        int token = t >> 2, part = t & 3;
        *(float4*)(&Bsh[token][part*4]) = *(const float4*)(dbc + (size_t)(m0+token)*48 + 16 + part*4);
    }
    float Aa[16], hs[16];
    #pragma unroll
    for(int s=0;s<16;s++){ Aa[s] = -__expf(A_log[d*16+s]); hs[s] = 0.f; }
    float sdt = 0.f;
    __syncthreads();
    float dt_n = dtM[(size_t)m0*DIN + d];
    float u_n  = u[(size_t)m0*DIN + d];
    for(int tt=0; tt<CLEN; tt++){
        float dtv = dt_n, uv = u_n;
        if(tt+1 < CLEN){
            dt_n = dtM[(size_t)(m0+tt+1)*DIN + d];
            u_n  = u[(size_t)(m0+tt+1)*DIN + d];
        }
        float du = dtv*uv;
        sdt += dtv;
        #pragma unroll
        for(int s=0;s<16;s++)
            hs[s] = hs[s]*__expf(dtv*Aa[s]) + du*Bsh[tt][s];
    }
    float* Sp = S + (((size_t)b*CHK + c)*DIN + d)*16;
    #pragma unroll
    for(int q=0;q<4;q++)
        *(float4*)(Sp + q*4) = make_float4(hs[q*4],hs[q*4+1],hs[q*4+2],hs[q*4+3]);
    sumdt[((size_t)b*CHK + c)*DIN + d] = sdt;
}

// ---------------- scan phase 2: serial combine over chunks -> H ----------------
__global__ __launch_bounds__(256) void k_scan2(const float* __restrict__ S,
                                               const float* __restrict__ sumdt,
                                               const float* __restrict__ A_log,
                                               float* __restrict__ H){
    int idx = blockIdx.x*256 + threadIdx.x;   // (b, d, s)
    int s = idx & 15;
    int d = (idx >> 4) & (DIN-1);
    int b = idx >> 13;
    float Aa = -__expf(A_log[d*DST + s]);
    float hh = 0.f;
    for(int c=0; c<CHK; c++){
        size_t o = (((size_t)b*CHK + c)*DIN + d)*DST + s;
        H[o] = hh;
        float P = __expf(Aa * sumdt[((size_t)b*CHK + c)*DIN + d]);
        hh = hh*P + S[o];
    }
}

// ---------------- scan phase 3 + gate + bf16 cast: yg[m,d] (bf16) ----------------
__global__ __launch_bounds__(256) void k_scan3(const float* __restrict__ dtM,
                                               const float* __restrict__ u,
                                               const float* __restrict__ dbc,
                                               const float* __restrict__ xz,
                                               const float* __restrict__ A_log,
                                               const float* __restrict__ Dpv,
                                               const float* __restrict__ H,
                                               unsigned short* __restrict__ yg){
    int b = blockIdx.y;
    int c = blockIdx.x >> 1;
    int d0 = (blockIdx.x & 1)*256;
    int t = threadIdx.x;
    int d = d0 + t;
    int m0 = b*LQ + c*CLEN;
    __shared__ float BCs[CLEN][36];   // [token][0:16]=B, [16:32]=C
    {
        int token = t >> 3, part = t & 7;
        *(float4*)(&BCs[token][part*4]) = *(const float4*)(dbc + (size_t)(m0+token)*48 + 16 + part*4);
    }
    float Aa[16], hs[16];
    #pragma unroll
    for(int s=0;s<16;s++) Aa[s] = -__expf(A_log[d*16+s]);
    const float* Hp = H + (((size_t)b*CHK + c)*DIN + d)*16;
    #pragma unroll
    for(int q=0;q<4;q++){
        float4 v = *(const float4*)(Hp + q*4);
        hs[q*4]=v.x; hs[q*4+1]=v.y; hs[q*4+2]=v.z; hs[q*4+3]=v.w;
    }
    float dp = Dpv[d];
    __syncthreads();
    float dt_n = dtM[(size_t)m0*DIN + d];
    float u_n  = u[(size_t)m0*DIN + d];
    for(int tt=0; tt<CLEN; tt++){
        float dtv = dt_n, uv = u_n;
        if(tt+1 < CLEN){
            dt_n = dtM[(size_t)(m0+tt+1)*DIN + d];
            u_n  = u[(size_t)(m0+tt+1)*DIN + d];
        }
        float du = dtv*uv;
        float y = 0.f;
        #pragma unroll
        for(int s=0;s<16;s++){
            hs[s] = hs[s]*__expf(dtv*Aa[s]) + du*BCs[tt][s];
            y += hs[s]*BCs[tt][16+s];
        }
        y += uv*dp;
        float z = xz[(size_t)(m0+tt)*1024 + 512 + d];
        yg[(size_t)(m0+tt)*DIN + d] = f2bf(y * fsilu(z));
    }
}

extern "C" void kernel_launch(void* const* d_in, const int* in_sizes, int n_in,
                              void* d_out, int out_size, void* d_ws, size_t ws_size,
                              hipStream_t stream){
    (void)in_sizes; (void)n_in; (void)out_size; (void)ws_size;
    const float* x        = (const float*)d_in[0];
    const float* ln_g     = (const float*)d_in[1];
    const float* ln_b     = (const float*)d_in[2];
    const float* in_w     = (const float*)d_in[3];
    const float* conv_w   = (const float*)d_in[4];
    const float* conv_b   = (const float*)d_in[5];
    const float* xproj_w  = (const float*)d_in[6];
    const float* dtproj_w = (const float*)d_in[7];
    const float* dtproj_b = (const float*)d_in[8];
    const float* A_log    = (const float*)d_in[9];
    const float* Dp       = (const float*)d_in[10];
    const float* out_w    = (const float*)d_in[11];
    float* h = (float*)d_out;
    float* ws = (float*)d_ws;

    // workspace layout (float offsets); total 43,618,304 floats (~174 MB; R1 proved 46.1M ok)
    float* xz   = ws;                              // 16,777,216
    float* u    = ws + 16777216;                   //  8,388,608
    float* dtM  = ws + 25165824;                   //  8,388,608
    float* dbc  = ws + 33554432;                   //    786,432
    float* R1   = ws + 34340864;                   //  4,194,304 (hn_bf / S / yg_bf, disjoint lifetimes)
    float* Hbuf = ws + 38535168;                   //  4,194,304 (aliases u_bf: dead before scan2 writes)
    float* sumdt= ws + 42729472;                   //    262,144
    unsigned short* inw_bf  = (unsigned short*)(ws + 42991616);  // 786,432 bf16
    unsigned short* outw_bf = (unsigned short*)(ws + 43384832);  // 393,216 bf16
    unsigned short* xw_bf   = (unsigned short*)(ws + 43581440);  //  73,728 bf16
    unsigned short* hn_bf = (unsigned short*)R1;
    unsigned short* yg_bf = (unsigned short*)R1;
    unsigned short* u_bf  = (unsigned short*)Hbuf;
    float* Sbuf = R1;

    k_cast<<<768, 256, 0, stream>>>(in_w,  inw_bf,  3*1024*DMD);
    k_cast<<<384, 256, 0, stream>>>(out_w, outw_bf, 3*DMD*DIN);
    k_cast<<<72,  256, 0, stream>>>(xproj_w, xw_bf, 3*48*DIN);
    k_copy<<<(MT*DMD/4 + 255)/256, 256, 0, stream>>>((const float4*)x, (float4*)h, MT*DMD/4);

    for(int li=0; li<3; li++){
        const float* Al = A_log + (size_t)li*DIN*DST;

        k_ln<<<MT/4, 256, 0, stream>>>(h, ln_g, ln_b, hn_bf);

        dim3 g1(MT/128, 1024/128);
        k_gemm_bf16<<<g1, 256, 0, stream>>>(hn_bf, inw_bf + (size_t)li*1024*DMD, xz,
                                            DMD, 1024, 0);

        dim3 gc(LQ/64, DIN/64, NB);
        k_conv<<<gc, 256, 0, stream>>>(xz, conv_w + (size_t)li*DIN*4, conv_b + (size_t)li*DIN,
                                       u, u_bf);

        k_xproj<<<MT/64, 256, 0, stream>>>(u_bf, xw_bf + (size_t)li*48*DIN, dbc);

        k_dt<<<MT/32, 256, 0, stream>>>(dbc, dtproj_w + (size_t)li*DIN*16,
                                        dtproj_b + (size_t)li*DIN, dtM);

        dim3 gs(2*CHK, NB);
        k_scan1<<<gs, 256, 0, stream>>>(dtM, u, dbc, Al, Sbuf, sumdt);

        k_scan2<<<(NB*DIN*DST)/256, 256, 0, stream>>>(Sbuf, sumdt, Al, Hbuf);

        k_scan3<<<gs, 256, 0, stream>>>(dtM, u, dbc, xz, Al, Dp + (size_t)li*DIN, Hbuf, yg_bf);

        dim3 g3(MT/128, DMD/128);
        k_gemm_bf16<<<g3, 256, 0, stream>>>(yg_bf, outw_bf + (size_t)li*DMD*DIN, h,
                                            DIN, DMD, 1);
    }
}